// Round 2
// baseline (1413.343 us; speedup 1.0000x reference)
//
#include <hip/hip_runtime.h>

// Problem constants (from reference): 16 clouds x 4096 pts, sample 1024, D=512
#define N_PER   4096
#define M_SAMP  1024
#define B_CL    16
#define D_FEAT  512
#define TPB     512
#define NWAVE   (TPB / 64)      // 8 waves
#define PPT     (N_PER / TPB)   // 8 points per thread (blocked: thread t owns t*8..t*8+7)

// ---------------------------------------------------------------------------
// DPP-based wave64 argmax reduction step: combine (v,i) with lane pattern CTRL.
// old = current value, so OOB/unsupplied lanes (e.g. row0 for bcast15) are
// no-ops (v2==v, i2==i -> no change). VALU latency, no DS pipe.
//   tie-break: greater val wins, equal val -> smaller idx wins (jnp.argmax)
// ---------------------------------------------------------------------------
template <int CTRL>
__device__ __forceinline__ void dpp_combine(float& v, int& i) {
    int vv = __builtin_amdgcn_update_dpp(__float_as_int(v), __float_as_int(v),
                                         CTRL, 0xF, 0xF, false);
    int ii = __builtin_amdgcn_update_dpp(i, i, CTRL, 0xF, 0xF, false);
    float v2 = __int_as_float(vv);
    if (v2 > v || (v2 == v && ii < i)) { v = v2; i = ii; }
}

// ---------------------------------------------------------------------------
// FPS: one workgroup per cloud. pos staged in LDS (float4), per-thread dist in
// registers. Exact jnp semantics:
//   d2 = ((dx*dx + dy*dy) + dz*dz) in f32, no FMA contraction
//   argmax = first occurrence of max
// ---------------------------------------------------------------------------
__global__ __launch_bounds__(TPB) void fps_kernel(const float* __restrict__ pos,
                                                  int* __restrict__ sidx) {
    __shared__ float4 spos[N_PER];       // 64 KiB
    __shared__ uint2  sw[2][NWAVE];      // double-buffered per-wave winners

    const int cloud = blockIdx.x;
    const int tid   = threadIdx.x;
    const float* posb = pos + (size_t)cloud * N_PER * 3;

    // stage cloud positions into LDS (coalesced global reads)
    for (int i = tid; i < N_PER * 3; i += TPB) {
        int p = i / 3, c = i - p * 3;
        ((float*)&spos[p])[c] = posb[i];
    }
    __syncthreads();

    // preload my 8 points + init dist
    float px[PPT], py[PPT], pz[PPT], dist[PPT];
    const int base = tid * PPT;
#pragma unroll
    for (int j = 0; j < PPT; ++j) {
        float4 v = spos[base + j];
        px[j] = v.x; py[j] = v.y; pz[j] = v.z;
        dist[j] = 1e30f;
    }

    int last = 0;
    if (tid == 0) sidx[cloud * M_SAMP] = 0;   // deterministic start at local 0

    const int wave = tid >> 6;
    const int lane = tid & 63;

    for (int s = 1; s < M_SAMP; ++s) {
        float4 lp = spos[last];               // broadcast LDS read (no conflict)

        float bv = -1.0f;                     // all dist >= 0, so always beaten
        int   bi = 0;
#pragma unroll
        for (int j = 0; j < PPT; ++j) {
            float dx = __fsub_rn(px[j], lp.x);
            float dy = __fsub_rn(py[j], lp.y);
            float dz = __fsub_rn(pz[j], lp.z);
            float d2 = __fadd_rn(__fadd_rn(__fmul_rn(dx, dx), __fmul_rn(dy, dy)),
                                 __fmul_rn(dz, dz));
            float dn = fminf(dist[j], d2);
            dist[j] = dn;
            // ascending j + strictly-greater keeps first occurrence
            if (dn > bv) { bv = dn; bi = base + j; }
        }

        // wave64 argmax via DPP (VALU latency, no DS ops):
        dpp_combine<0xB1>(bv, bi);    // quad_perm [1,0,3,2]  : xor 1
        dpp_combine<0x4E>(bv, bi);    // quad_perm [2,3,0,1]  : xor 2
        dpp_combine<0x141>(bv, bi);   // row_half_mirror      : pairs across quads
        dpp_combine<0x140>(bv, bi);   // row_mirror           : full row of 16
        dpp_combine<0x142>(bv, bi);   // row_bcast15          : row1=r0|r1, row3=r2|r3
        dpp_combine<0x143>(bv, bi);   // row_bcast31          : row3 = all 64
        // lane 63 now holds the wave winner

        // cross-wave merge via LDS (double-buffered, single barrier per step)
        const int buf = s & 1;
        if (lane == 63) sw[buf][wave] = make_uint2(__float_as_uint(bv), (unsigned)bi);
        __syncthreads();
        uint2 p0 = sw[buf][0];
        float fv = __uint_as_float(p0.x);
        int   fi = (int)p0.y;
#pragma unroll
        for (int w = 1; w < NWAVE; ++w) {
            uint2 p  = sw[buf][w];
            float v2 = __uint_as_float(p.x);
            int   i2 = (int)p.y;
            if (v2 > fv || (v2 == fv && i2 < fi)) { fv = v2; fi = i2; }
        }
        last = fi;
        if (tid == 0) sidx[cloud * M_SAMP + s] = last;  // local idx; globalized in gather
    }
}

// ---------------------------------------------------------------------------
// Gather x rows: out[r][:] = x[g][:], float4-vectorized. 16384 rows x 128 f4.
// sidx holds LOCAL per-cloud indices; globalize with cloud offset r/M*N_PER.
// ---------------------------------------------------------------------------
__global__ __launch_bounds__(256) void gather_x_kernel(const float4* __restrict__ x4,
                                                       const int* __restrict__ sidx,
                                                       float4* __restrict__ out4) {
    int id = blockIdx.x * 256 + threadIdx.x;     // 0 .. 16384*128-1
    int r  = id >> 7;                            // row in output
    int c  = id & 127;                           // float4 column
    int g  = sidx[r] + (r >> 10 << 12);          // + (r/1024)*4096 global offset
    out4[id] = x4[(size_t)g * (D_FEAT / 4) + c];
}

// ---------------------------------------------------------------------------
// Gather pos (3 f32/row) and batch (as float). 16384 threads.
// ---------------------------------------------------------------------------
__global__ __launch_bounds__(256) void gather_pb_kernel(const float* __restrict__ pos,
                                                        const int* __restrict__ batch,
                                                        const int* __restrict__ sidx,
                                                        float* __restrict__ out_pos,
                                                        float* __restrict__ out_batch) {
    int r = blockIdx.x * 256 + threadIdx.x;      // 0 .. 16383
    int g = sidx[r] + (r >> 10 << 12);
    out_pos[r * 3 + 0] = pos[g * 3 + 0];
    out_pos[r * 3 + 1] = pos[g * 3 + 1];
    out_pos[r * 3 + 2] = pos[g * 3 + 2];
    out_batch[r] = (float)batch[g];
}

extern "C" void kernel_launch(void* const* d_in, const int* in_sizes, int n_in,
                              void* d_out, int out_size, void* d_ws, size_t ws_size,
                              hipStream_t stream) {
    const float* x     = (const float*)d_in[0];   // [65536,512] f32
    const float* pos   = (const float*)d_in[1];   // [65536,3]   f32
    const int*   batch = (const int*)d_in[2];     // [65536]     i32

    int* sidx = (int*)d_ws;                       // [16384] local sampled indices

    float* out   = (float*)d_out;
    float* out_x = out;                                            // 16384*512
    float* out_p = out + (size_t)B_CL * M_SAMP * D_FEAT;           // 16384*3
    float* out_b = out_p + (size_t)B_CL * M_SAMP * 3;              // 16384

    // 1) FPS: 16 blocks (one per cloud), 512 threads
    fps_kernel<<<B_CL, TPB, 0, stream>>>(pos, sidx);

    // 2) x gather: 16384 rows * 128 float4 / 256 threads = 8192 blocks
    gather_x_kernel<<<(B_CL * M_SAMP * (D_FEAT / 4)) / 256, 256, 0, stream>>>(
        (const float4*)x, sidx, (float4*)out_x);

    // 3) pos + batch gather: 16384 / 256 = 64 blocks
    gather_pb_kernel<<<(B_CL * M_SAMP) / 256, 256, 0, stream>>>(
        pos, batch, sidx, out_p, out_b);
}

// Round 3
// 1215.856 us; speedup vs baseline: 1.1624x; 1.1624x over previous
//
#include <hip/hip_runtime.h>

// Problem constants (from reference): 16 clouds x 4096 pts, sample 1024, D=512
#define N_PER   4096
#define M_SAMP  1024
#define B_CL    16
#define D_FEAT  512
#define TPB     256
#define NWAVE   (TPB / 64)      // 4 waves
#define PPT     (N_PER / TPB)   // 16 points per thread (thread t owns t*16..t*16+15)

// ---------------------------------------------------------------------------
// DPP 5-tuple argmax combine: (key u64 desc) carrying winner coords (x,y,z).
// key = (float_bits(val) << 32) | (4095 - idx):
//   max key == max val, tie -> min idx  (exact jnp.argmax first-occurrence)
// Lanes not supplied by the DPP pattern combine with themselves (no-op).
// ---------------------------------------------------------------------------
template <int CTRL>
__device__ __forceinline__ void dpp_combine5(unsigned& khi, unsigned& klo,
                                             float& x, float& y, float& z) {
    unsigned khi2 = (unsigned)__builtin_amdgcn_update_dpp((int)khi, (int)khi, CTRL, 0xF, 0xF, false);
    unsigned klo2 = (unsigned)__builtin_amdgcn_update_dpp((int)klo, (int)klo, CTRL, 0xF, 0xF, false);
    int xi = __builtin_amdgcn_update_dpp(__float_as_int(x), __float_as_int(x), CTRL, 0xF, 0xF, false);
    int yi = __builtin_amdgcn_update_dpp(__float_as_int(y), __float_as_int(y), CTRL, 0xF, 0xF, false);
    int zi = __builtin_amdgcn_update_dpp(__float_as_int(z), __float_as_int(z), CTRL, 0xF, 0xF, false);
    unsigned long long k  = ((unsigned long long)khi  << 32) | klo;
    unsigned long long k2 = ((unsigned long long)khi2 << 32) | klo2;
    if (k2 > k) {
        khi = khi2; klo = klo2;
        x = __int_as_float(xi); y = __int_as_float(yi); z = __int_as_float(zi);
    }
}

// ---------------------------------------------------------------------------
// FPS: one workgroup per cloud. pos preloaded global->registers (16 pts/thr),
// dist in registers. NO per-step pos read: winner coords ride the reduction.
// Exact jnp semantics: d2 = ((dx*dx + dy*dy) + dz*dz) f32, no FMA contraction;
// argmax = first occurrence of max.
// ---------------------------------------------------------------------------
__global__ __launch_bounds__(TPB) void fps_kernel(const float* __restrict__ pos,
                                                  int* __restrict__ sidx) {
    // merge slots: [buf][wave] = {khi, klo, x, y, z, pad...}
    __shared__ unsigned sw[2][NWAVE][8];

    const int cloud = blockIdx.x;
    const int tid   = threadIdx.x;
    const float* posb = pos + (size_t)cloud * N_PER * 3;

    // preload my 16 points straight from global (48 floats = 12 aligned float4)
    float f[48];
    {
        const float4* posb4 = (const float4*)posb + tid * 12;
#pragma unroll
        for (int v = 0; v < 12; ++v) {
            float4 t = posb4[v];
            f[4 * v + 0] = t.x; f[4 * v + 1] = t.y;
            f[4 * v + 2] = t.z; f[4 * v + 3] = t.w;
        }
    }
    float px[PPT], py[PPT], pz[PPT], dist[PPT];
    const int base = tid * PPT;
#pragma unroll
    for (int j = 0; j < PPT; ++j) {
        px[j] = f[3 * j]; py[j] = f[3 * j + 1]; pz[j] = f[3 * j + 2];
        dist[j] = 1e30f;
    }

    // current "last" point = local point 0 (deterministic start)
    float lx = posb[0], ly = posb[1], lz = posb[2];
    if (tid == 0) sidx[cloud * M_SAMP] = 0;

    const int wave = tid >> 6;
    const int lane = tid & 63;

    for (int s = 1; s < M_SAMP; ++s) {
        // distance update + per-thread argmax (ascending j => first occurrence)
        float bv = -1.0f;
        int   bi = 0;
#pragma unroll
        for (int j = 0; j < PPT; ++j) {
            float dx = __fsub_rn(px[j], lx);
            float dy = __fsub_rn(py[j], ly);
            float dz = __fsub_rn(pz[j], lz);
            float d2 = __fadd_rn(__fadd_rn(__fmul_rn(dx, dx), __fmul_rn(dy, dy)),
                                 __fmul_rn(dz, dz));
            float dn = fminf(dist[j], d2);
            dist[j] = dn;
            if (dn > bv) { bv = dn; bi = j; }
        }
        // pack key (bv >= 0 so float bits are monotone) + candidate coords
        unsigned khi = __float_as_uint(bv);
        unsigned klo = (unsigned)(N_PER - 1 - (base + bi));
        float cx = px[bi], cy = py[bi], cz = pz[bi];

        // wave64 argmax via DPP (VALU-only, carries coords)
        dpp_combine5<0xB1>(khi, klo, cx, cy, cz);    // quad_perm xor1
        dpp_combine5<0x4E>(khi, klo, cx, cy, cz);    // quad_perm xor2
        dpp_combine5<0x141>(khi, klo, cx, cy, cz);   // row_half_mirror
        dpp_combine5<0x140>(khi, klo, cx, cy, cz);   // row_mirror
        dpp_combine5<0x142>(khi, klo, cx, cy, cz);   // row_bcast15
        dpp_combine5<0x143>(khi, klo, cx, cy, cz);   // row_bcast31
        // lane 63 holds the wave winner

        const int buf = s & 1;
        if (lane == 63) {
            sw[buf][wave][0] = khi; sw[buf][wave][1] = klo;
            sw[buf][wave][2] = __float_as_uint(cx);
            sw[buf][wave][3] = __float_as_uint(cy);
            sw[buf][wave][4] = __float_as_uint(cz);
        }
        __syncthreads();

        // cross-wave merge: broadcast reads, unique keys -> exact winner
        unsigned wkhi = sw[buf][0][0], wklo = sw[buf][0][1];
        unsigned wx = sw[buf][0][2], wy = sw[buf][0][3], wz = sw[buf][0][4];
#pragma unroll
        for (int w = 1; w < NWAVE; ++w) {
            unsigned h2 = sw[buf][w][0], l2 = sw[buf][w][1];
            unsigned long long k  = ((unsigned long long)wkhi << 32) | wklo;
            unsigned long long k2 = ((unsigned long long)h2   << 32) | l2;
            if (k2 > k) {
                wkhi = h2; wklo = l2;
                wx = sw[buf][w][2]; wy = sw[buf][w][3]; wz = sw[buf][w][4];
            }
        }
        lx = __uint_as_float(wx); ly = __uint_as_float(wy); lz = __uint_as_float(wz);
        if (tid == 0) sidx[cloud * M_SAMP + s] = N_PER - 1 - (int)wklo;
    }
}

// ---------------------------------------------------------------------------
// Gather x rows: out[r][:] = x[g][:], float4-vectorized. 16384 rows x 128 f4.
// sidx holds LOCAL per-cloud indices; globalize with cloud offset r/M*N_PER.
// ---------------------------------------------------------------------------
__global__ __launch_bounds__(256) void gather_x_kernel(const float4* __restrict__ x4,
                                                       const int* __restrict__ sidx,
                                                       float4* __restrict__ out4) {
    int id = blockIdx.x * 256 + threadIdx.x;     // 0 .. 16384*128-1
    int r  = id >> 7;                            // row in output
    int c  = id & 127;                           // float4 column
    int g  = sidx[r] + (r >> 10 << 12);          // + (r/1024)*4096 global offset
    out4[id] = x4[(size_t)g * (D_FEAT / 4) + c];
}

// ---------------------------------------------------------------------------
// Gather pos (3 f32/row) and batch (as float). 16384 threads.
// ---------------------------------------------------------------------------
__global__ __launch_bounds__(256) void gather_pb_kernel(const float* __restrict__ pos,
                                                        const int* __restrict__ batch,
                                                        const int* __restrict__ sidx,
                                                        float* __restrict__ out_pos,
                                                        float* __restrict__ out_batch) {
    int r = blockIdx.x * 256 + threadIdx.x;      // 0 .. 16383
    int g = sidx[r] + (r >> 10 << 12);
    out_pos[r * 3 + 0] = pos[g * 3 + 0];
    out_pos[r * 3 + 1] = pos[g * 3 + 1];
    out_pos[r * 3 + 2] = pos[g * 3 + 2];
    out_batch[r] = (float)batch[g];
}

extern "C" void kernel_launch(void* const* d_in, const int* in_sizes, int n_in,
                              void* d_out, int out_size, void* d_ws, size_t ws_size,
                              hipStream_t stream) {
    const float* x     = (const float*)d_in[0];   // [65536,512] f32
    const float* pos   = (const float*)d_in[1];   // [65536,3]   f32
    const int*   batch = (const int*)d_in[2];     // [65536]     i32

    int* sidx = (int*)d_ws;                       // [16384] local sampled indices

    float* out   = (float*)d_out;
    float* out_x = out;                                            // 16384*512
    float* out_p = out + (size_t)B_CL * M_SAMP * D_FEAT;           // 16384*3
    float* out_b = out_p + (size_t)B_CL * M_SAMP * 3;              // 16384

    // 1) FPS: 16 blocks (one per cloud), 256 threads
    fps_kernel<<<B_CL, TPB, 0, stream>>>(pos, sidx);

    // 2) x gather: 16384 rows * 128 float4 / 256 threads = 8192 blocks
    gather_x_kernel<<<(B_CL * M_SAMP * (D_FEAT / 4)) / 256, 256, 0, stream>>>(
        (const float4*)x, sidx, (float4*)out_x);

    // 3) pos + batch gather: 16384 / 256 = 64 blocks
    gather_pb_kernel<<<(B_CL * M_SAMP) / 256, 256, 0, stream>>>(
        pos, batch, sidx, out_p, out_b);
}

// Round 4
// 1112.864 us; speedup vs baseline: 1.2700x; 1.0925x over previous
//
#include <hip/hip_runtime.h>

// Problem constants (from reference): 16 clouds x 4096 pts, sample 1024, D=512
#define N_PER   4096
#define M_SAMP  1024
#define B_CL    16
#define D_FEAT  512
#define TPB     256
#define NWAVE   (TPB / 64)      // 4 waves
#define PPT     (N_PER / TPB)   // 16 points per thread (thread t owns t*16..t*16+15)

// ---------------------------------------------------------------------------
// DPP 5-tuple argmax combine: key u64 desc, carrying winner coords (x,y,z).
// key = (float_bits(val) << 32) | (4095 - idx):
//   max key == max val; tie -> min idx  (exact jnp.argmax first-occurrence)
// Lanes not supplied by the DPP pattern combine with themselves (no-op).
// ---------------------------------------------------------------------------
template <int CTRL>
__device__ __forceinline__ void dpp_combine5(unsigned& khi, unsigned& klo,
                                             float& x, float& y, float& z) {
    unsigned khi2 = (unsigned)__builtin_amdgcn_update_dpp((int)khi, (int)khi, CTRL, 0xF, 0xF, false);
    unsigned klo2 = (unsigned)__builtin_amdgcn_update_dpp((int)klo, (int)klo, CTRL, 0xF, 0xF, false);
    int xi = __builtin_amdgcn_update_dpp(__float_as_int(x), __float_as_int(x), CTRL, 0xF, 0xF, false);
    int yi = __builtin_amdgcn_update_dpp(__float_as_int(y), __float_as_int(y), CTRL, 0xF, 0xF, false);
    int zi = __builtin_amdgcn_update_dpp(__float_as_int(z), __float_as_int(z), CTRL, 0xF, 0xF, false);
    unsigned long long k  = ((unsigned long long)khi  << 32) | klo;
    unsigned long long k2 = ((unsigned long long)khi2 << 32) | klo2;
    if (k2 > k) {
        khi = khi2; klo = klo2;
        x = __int_as_float(xi); y = __int_as_float(yi); z = __int_as_float(zi);
    }
}

// ---------------------------------------------------------------------------
// FPS: one workgroup per cloud. pos preloaded global->registers (16 pts/thr,
// ALL statically indexed -> stays in VGPRs). Winner coords ride the reduction
// (cndmask selects in the j-loop, no dynamic register indexing). Sampled
// indices buffered in LDS, dumped once at the end (no global store in loop).
// Exact jnp semantics: d2 = ((dx*dx + dy*dy) + dz*dz) f32, no FMA contraction;
// argmax = first occurrence of max.
// ---------------------------------------------------------------------------
__global__ __launch_bounds__(TPB) void fps_kernel(const float* __restrict__ pos,
                                                  int* __restrict__ sidx) {
    __shared__ unsigned sw[2][NWAVE][8];   // [buf][wave] = {khi, klo, x, y, z}
    __shared__ int      sloc[M_SAMP];      // sampled local indices (4 KiB)

    const int cloud = blockIdx.x;
    const int tid   = threadIdx.x;
    const float* posb = pos + (size_t)cloud * N_PER * 3;

    // preload my 16 points straight from global (48 floats = 12 aligned float4)
    float px[PPT], py[PPT], pz[PPT], dist[PPT];
    {
        float f[48];
        const float4* posb4 = (const float4*)posb + tid * 12;
#pragma unroll
        for (int v = 0; v < 12; ++v) {
            float4 t = posb4[v];
            f[4 * v + 0] = t.x; f[4 * v + 1] = t.y;
            f[4 * v + 2] = t.z; f[4 * v + 3] = t.w;
        }
#pragma unroll
        for (int j = 0; j < PPT; ++j) {
            px[j] = f[3 * j]; py[j] = f[3 * j + 1]; pz[j] = f[3 * j + 2];
            dist[j] = 1e30f;
        }
    }
    const int base = tid * PPT;

    // current "last" point = local point 0 (deterministic start)
    float lx = posb[0], ly = posb[1], lz = posb[2];
    if (tid == 0) sloc[0] = 0;

    const int wave = tid >> 6;
    const int lane = tid & 63;

    for (int s = 1; s < M_SAMP; ++s) {
        // distance update + per-thread argmax carrying coords (all cndmask,
        // static register indices; ascending j + strict '>' => first occurrence)
        float bv = -1.0f;                 // all dist >= 0, so always beaten
        int   bi = 0;
        float cx = px[0], cy = py[0], cz = pz[0];
#pragma unroll
        for (int j = 0; j < PPT; ++j) {
            float dx = __fsub_rn(px[j], lx);
            float dy = __fsub_rn(py[j], ly);
            float dz = __fsub_rn(pz[j], lz);
            float d2 = __fadd_rn(__fadd_rn(__fmul_rn(dx, dx), __fmul_rn(dy, dy)),
                                 __fmul_rn(dz, dz));
            float dn = fminf(dist[j], d2);
            dist[j] = dn;
            bool t = dn > bv;
            bv = t ? dn : bv;
            bi = t ? j : bi;
            cx = t ? px[j] : cx;
            cy = t ? py[j] : cy;
            cz = t ? pz[j] : cz;
        }
        unsigned khi = __float_as_uint(bv);                  // bv >= 0: bits monotone
        unsigned klo = (unsigned)(N_PER - 1 - (base + bi));  // tie -> smaller idx wins

        // wave64 argmax via DPP (VALU-only, carries coords)
        dpp_combine5<0xB1>(khi, klo, cx, cy, cz);    // quad_perm xor1
        dpp_combine5<0x4E>(khi, klo, cx, cy, cz);    // quad_perm xor2
        dpp_combine5<0x141>(khi, klo, cx, cy, cz);   // row_half_mirror
        dpp_combine5<0x140>(khi, klo, cx, cy, cz);   // row_mirror
        dpp_combine5<0x142>(khi, klo, cx, cy, cz);   // row_bcast15
        dpp_combine5<0x143>(khi, klo, cx, cy, cz);   // row_bcast31
        // lane 63 holds the wave winner

        const int buf = s & 1;
        if (lane == 63) {
            sw[buf][wave][0] = khi; sw[buf][wave][1] = klo;
            sw[buf][wave][2] = __float_as_uint(cx);
            sw[buf][wave][3] = __float_as_uint(cy);
            sw[buf][wave][4] = __float_as_uint(cz);
        }
        __syncthreads();   // only LDS ops outstanding -> cheap lgkm drain

        // cross-wave merge: broadcast reads, unique keys -> exact winner
        unsigned wkhi = sw[buf][0][0], wklo = sw[buf][0][1];
        unsigned wx = sw[buf][0][2], wy = sw[buf][0][3], wz = sw[buf][0][4];
#pragma unroll
        for (int w = 1; w < NWAVE; ++w) {
            unsigned h2 = sw[buf][w][0], l2 = sw[buf][w][1];
            unsigned long long k  = ((unsigned long long)wkhi << 32) | wklo;
            unsigned long long k2 = ((unsigned long long)h2   << 32) | l2;
            if (k2 > k) {
                wkhi = h2; wklo = l2;
                wx = sw[buf][w][2]; wy = sw[buf][w][3]; wz = sw[buf][w][4];
            }
        }
        lx = __uint_as_float(wx); ly = __uint_as_float(wy); lz = __uint_as_float(wz);
        if (tid == 0) sloc[s] = N_PER - 1 - (int)wklo;   // LDS, drained next barrier
    }

    // dump sampled indices to global once (coalesced)
    __syncthreads();
    for (int i = tid; i < M_SAMP; i += TPB)
        sidx[cloud * M_SAMP + i] = sloc[i];
}

// ---------------------------------------------------------------------------
// Gather x rows: out[r][:] = x[g][:], float4-vectorized. 16384 rows x 128 f4.
// sidx holds LOCAL per-cloud indices; globalize with cloud offset r/M*N_PER.
// ---------------------------------------------------------------------------
__global__ __launch_bounds__(256) void gather_x_kernel(const float4* __restrict__ x4,
                                                       const int* __restrict__ sidx,
                                                       float4* __restrict__ out4) {
    int id = blockIdx.x * 256 + threadIdx.x;     // 0 .. 16384*128-1
    int r  = id >> 7;                            // row in output
    int c  = id & 127;                           // float4 column
    int g  = sidx[r] + (r >> 10 << 12);          // + (r/1024)*4096 global offset
    out4[id] = x4[(size_t)g * (D_FEAT / 4) + c];
}

// ---------------------------------------------------------------------------
// Gather pos (3 f32/row) and batch (as float). 16384 threads.
// ---------------------------------------------------------------------------
__global__ __launch_bounds__(256) void gather_pb_kernel(const float* __restrict__ pos,
                                                        const int* __restrict__ batch,
                                                        const int* __restrict__ sidx,
                                                        float* __restrict__ out_pos,
                                                        float* __restrict__ out_batch) {
    int r = blockIdx.x * 256 + threadIdx.x;      // 0 .. 16383
    int g = sidx[r] + (r >> 10 << 12);
    out_pos[r * 3 + 0] = pos[g * 3 + 0];
    out_pos[r * 3 + 1] = pos[g * 3 + 1];
    out_pos[r * 3 + 2] = pos[g * 3 + 2];
    out_batch[r] = (float)batch[g];
}

extern "C" void kernel_launch(void* const* d_in, const int* in_sizes, int n_in,
                              void* d_out, int out_size, void* d_ws, size_t ws_size,
                              hipStream_t stream) {
    const float* x     = (const float*)d_in[0];   // [65536,512] f32
    const float* pos   = (const float*)d_in[1];   // [65536,3]   f32
    const int*   batch = (const int*)d_in[2];     // [65536]     i32

    int* sidx = (int*)d_ws;                       // [16384] local sampled indices

    float* out   = (float*)d_out;
    float* out_x = out;                                            // 16384*512
    float* out_p = out + (size_t)B_CL * M_SAMP * D_FEAT;           // 16384*3
    float* out_b = out_p + (size_t)B_CL * M_SAMP * 3;              // 16384

    // 1) FPS: 16 blocks (one per cloud), 256 threads
    fps_kernel<<<B_CL, TPB, 0, stream>>>(pos, sidx);

    // 2) x gather: 16384 rows * 128 float4 / 256 threads = 8192 blocks
    gather_x_kernel<<<(B_CL * M_SAMP * (D_FEAT / 4)) / 256, 256, 0, stream>>>(
        (const float4*)x, sidx, (float4*)out_x);

    // 3) pos + batch gather: 16384 / 256 = 64 blocks
    gather_pb_kernel<<<(B_CL * M_SAMP) / 256, 256, 0, stream>>>(
        pos, batch, sidx, out_p, out_b);
}